// Round 5
// baseline (565.795 us; speedup 1.0000x reference)
//
#include <hip/hip_runtime.h>

// SimpleSelfAttention: B=16, S=2048, E=1024, fp32 in/out.
// out[b] = mean_q softmax(QK^T/32)·V == (Σ_k w[b,k]·x[b,k,:]) @ Wv^T + bv.
// Softmax shift-invariance: QK^T ≡ x·(Wq^T·Wk)·x^T + 1·v^T, v = x·(Wk^T·bq).
// R9: 256²/8-phase port REGRESSED (158.6 vs 141.9 µs — K=1024 has only 16
// K-tiles; 1 block/CU kills the TLP that covers fill/drain; m248 K=1024
// data agrees). Revert to 128² gemm_bt and instead:
//  (1) reg-staged 2-phase K-loop: read whole tile to regs, barrier, stage
//      next tile into the SAME 32KB buffer, MFMA from regs, vmcnt(0)+barrier
//      — stage latency hides under MFMA within-block (plus 3-block TLP).
//  (2) XCD-aware bijective block swizzle (grids %8==0): batch x-panel stays
//      L2-resident per XCD (FETCH 295MB -> ~150MB expected).
// Keep: fp8 π-permuted e-store, fp8 colsum, bf16 xbar, split-E out.

#define B_ 16
#define S_ 2048
#define E_ 1024

typedef __bf16 bf16x8 __attribute__((ext_vector_type(8)));
typedef float f32x4 __attribute__((ext_vector_type(4)));
typedef float f32x2 __attribute__((ext_vector_type(2)));

__device__ __forceinline__ unsigned short f2bf(float f) {
  unsigned int u = __float_as_uint(f);
  u = (u + 0x7FFFu + ((u >> 16) & 1u)) >> 16;  // RNE; finite inputs
  return (unsigned short)u;
}

// ---- g[e] = Σ_f wk[f,e]·bq[f] ---------------------------------------------
__global__ __launch_bounds__(256) void gvec_kernel(
    const float* __restrict__ wk, const float* __restrict__ bq,
    float* __restrict__ g) {
  const int e = blockIdx.x * 256 + threadIdx.x;
  const int f0 = blockIdx.y * 32;
  float acc = 0.f;
#pragma unroll
  for (int i = 0; i < 32; ++i) acc += wk[(size_t)(f0 + i) * E_ + e] * bq[f0 + i];
  atomicAdd(&g[e], acc);
}

// ---- cast x -> bf16 AND vs[row] = (x_row · g)/32 ; block == one row -------
__global__ __launch_bounds__(256) void cast_x_v_kernel(
    const float* __restrict__ x, const float* __restrict__ g,
    unsigned short* __restrict__ xbf, float* __restrict__ vs) {
  const int row = blockIdx.x, t = threadIdx.x;
  const size_t i = (size_t)row * E_ + t * 4;
  float4 v = *(const float4*)(x + i);
  float4 gv = *(const float4*)(g + t * 4);
  ushort4 o;
  o.x = f2bf(v.x); o.y = f2bf(v.y); o.z = f2bf(v.z); o.w = f2bf(v.w);
  *(ushort4*)(xbf + i) = o;
  float p = v.x * gv.x + v.y * gv.y + v.z * gv.z + v.w * gv.w;
#pragma unroll
  for (int off = 32; off >= 1; off >>= 1) p += __shfl_xor(p, off);
  __shared__ float wsp[4];
  if ((t & 63) == 0) wsp[t >> 6] = p;
  __syncthreads();
  if (t == 0) vs[row] = (wsp[0] + wsp[1] + wsp[2] + wsp[3]) * 0.03125f;
}

// ---- transpose-cast: dst[e,f] = bf16(src[f,e]), 1024x1024 -----------------
__global__ __launch_bounds__(256) void tcast_kernel(
    const float* __restrict__ src, unsigned short* __restrict__ dst) {
  __shared__ float tile[32][33];
  const int tx = threadIdx.x & 31, ty = threadIdx.x >> 5;
  const int f0 = blockIdx.y * 32, e0 = blockIdx.x * 32;
#pragma unroll
  for (int j = 0; j < 4; ++j)
    tile[ty + 8 * j][tx] = src[(size_t)(f0 + ty + 8 * j) * E_ + e0 + tx];
  __syncthreads();
#pragma unroll
  for (int j = 0; j < 4; ++j)
    dst[(size_t)(e0 + ty + 8 * j) * E_ + f0 + tx] = f2bf(tile[tx][ty + 8 * j]);
}

// ---- bf16 MFMA GEMM, 128x128 tile, BK=64, 4 waves, 16x16x32 MFMA ----------
// Reg-staged 2-phase loop + XCD-aware block swizzle (R9).
// MODE 0: C(bf16) = A·B^T            (Mt, y — no bias)
// MODE 1: e = exp(A·B^T·scale + vs[bz*S+col]); fp8-e4m3 π-permuted packed
//         store (dword per (row, 64-col grp): byte ni -> col grp*64+16ni+lr);
//         fp32 rowsum via 16-lane shfl + atomic.
template <int MODE>
__global__ __launch_bounds__(256, 2) void gemm_bt(
    const unsigned short* __restrict__ A, const unsigned short* __restrict__ Bm,
    void* __restrict__ Cout, const float* __restrict__ vs,
    float* __restrict__ rowsum, float scale,
    int K, int lda, int ldb, int ldc,
    long long strideA, long long strideB, long long strideC) {
  __shared__ unsigned short As[128 * 64];  // 16 KB
  __shared__ unsigned short Bs[128 * 64];  // 16 KB

  const int tid = threadIdx.x;
  const int wave = tid >> 6;
  const int lane = tid & 63;

  // XCD-aware bijective swizzle: XCD k (= lin%8) owns tiles [k*cpx,(k+1)*cpx)
  // walked x-fastest -> per-XCD L2 keeps the batch's B-panel resident.
  // All gemm_bt grids have nwg % 8 == 0 (64 / 2048 / 4096).
  const unsigned nwg = gridDim.x * gridDim.y * gridDim.z;
  const unsigned lin =
      blockIdx.x + gridDim.x * (blockIdx.y + gridDim.y * blockIdx.z);
  const unsigned cpx = nwg >> 3;
  const unsigned tz = (lin & 7) * cpx + (lin >> 3);
  const unsigned bxi = tz % gridDim.x;
  const unsigned rest = tz / gridDim.x;
  const unsigned byi = rest % gridDim.y;
  const unsigned bz = rest / gridDim.y;

  const unsigned short* Ab = A + (size_t)bz * strideA;
  const unsigned short* Bb = Bm + (size_t)bz * strideB;
  const int rowBase = byi * 128;
  const int colBase = bxi * 128;

  const int waveM = wave >> 1, waveN = wave & 1;
  const int lrow = lane & 15, lq = lane >> 4;

  const int rsub = lane >> 3;                   // row within 8-row chunk
  const int gOff = (((lane & 7) ^ rsub) << 3);  // swizzled source granule

  f32x4 acc[4][4];
#pragma unroll
  for (int i = 0; i < 4; ++i)
#pragma unroll
    for (int j = 0; j < 4; ++j) {
      f32x4 z = {0.f, 0.f, 0.f, 0.f};
      acc[i][j] = z;
    }

  // stage K-chunk kk into As/Bs (8 global_load_lds, width 16)
  auto stage = [&](int kk) {
#pragma unroll
    for (int i = 0; i < 4; ++i) {
      const int chunk = wave * 4 + i;
      const int r = chunk * 8 + rsub;
      const unsigned short* ga = Ab + (size_t)(rowBase + r) * lda + (kk + gOff);
      const unsigned short* gb = Bb + (size_t)(colBase + r) * ldb + (kk + gOff);
      __builtin_amdgcn_global_load_lds(
          (const __attribute__((address_space(1))) void*)ga,
          (__attribute__((address_space(3))) void*)(&As[chunk * 512]), 16, 0, 0);
      __builtin_amdgcn_global_load_lds(
          (const __attribute__((address_space(1))) void*)gb,
          (__attribute__((address_space(3))) void*)(&Bs[chunk * 512]), 16, 0, 0);
    }
  };

  // prologue: stage tile 0 and drain
  stage(0);
  asm volatile("s_waitcnt vmcnt(0)" ::: "memory");
  __builtin_amdgcn_s_barrier();

  for (int k0 = 0; k0 < K; k0 += 64) {
    // phase A: read the WHOLE tile into registers (16 x ds_read_b128)
    bf16x8 af[4][2], bfv[4][2];
#pragma unroll
    for (int ks = 0; ks < 2; ++ks) {
      const int gg = (((ks * 4 + lq) ^ (lrow & 7)) << 3);
#pragma unroll
      for (int mi = 0; mi < 4; ++mi)
        af[mi][ks] =
            *(const bf16x8*)(&As[(waveM * 64 + mi * 16 + lrow) * 64 + gg]);
#pragma unroll
      for (int ni = 0; ni < 4; ++ni)
        bfv[ni][ks] =
            *(const bf16x8*)(&Bs[(waveN * 64 + ni * 16 + lrow) * 64 + gg]);
    }
    asm volatile("s_waitcnt lgkmcnt(0)" ::: "memory");  // own reads in regs
    __builtin_amdgcn_s_barrier();  // all waves done reading -> LDS reusable

    // phase B: issue next-tile stage into the SAME buffer, then MFMA from
    // regs — the 8 loads' latency hides under 32 MFMAs (+ other blocks).
    if (k0 + 64 < K) stage(k0 + 64);
#pragma unroll
    for (int ks = 0; ks < 2; ++ks)
#pragma unroll
      for (int mi = 0; mi < 4; ++mi)
#pragma unroll
        for (int ni = 0; ni < 4; ++ni)
          acc[mi][ni] = __builtin_amdgcn_mfma_f32_16x16x32_bf16(
              af[mi][ks], bfv[ni][ks], acc[mi][ni], 0, 0, 0);
    asm volatile("s_waitcnt vmcnt(0)" ::: "memory");  // staged loads landed
    __builtin_amdgcn_s_barrier();
  }

  // epilogue: C/D layout col=lane&15, row=(lane>>4)*4+reg  [m89-verified]
  if constexpr (MODE == 0) {
    unsigned short* Cb = (unsigned short*)Cout;
#pragma unroll
    for (int mi = 0; mi < 4; ++mi) {
      const int grow = rowBase + waveM * 64 + mi * 16 + lq * 4;
#pragma unroll
      for (int ni = 0; ni < 4; ++ni) {
        const int gcol = colBase + waveN * 64 + ni * 16 + lrow;
#pragma unroll
        for (int r = 0; r < 4; ++r)
          Cb[(size_t)(grow + r) * ldc + gcol] = f2bf(acc[mi][ni][r]);
      }
    }
  } else {
    unsigned char* Eb = (unsigned char*)Cout + (size_t)bz * strideC;
    float* rs = rowsum + (size_t)bz * S_;
    const float* vsb = vs + (size_t)bz * S_;
    float badd[4];
#pragma unroll
    for (int ni = 0; ni < 4; ++ni)
      badd[ni] = vsb[colBase + waveN * 64 + ni * 16 + lrow];
#pragma unroll
    for (int mi = 0; mi < 4; ++mi) {
      const int grow = rowBase + waveM * 64 + mi * 16 + lq * 4;
#pragma unroll
      for (int r = 0; r < 4; ++r) {
        float e[4];
        float partial = 0.f;
#pragma unroll
        for (int ni = 0; ni < 4; ++ni) {
          e[ni] = __expf(acc[mi][ni][r] * scale + badd[ni]);
          partial += e[ni];
        }
        unsigned int pk = 0;
        pk = __builtin_amdgcn_cvt_pk_fp8_f32(e[0], e[1], pk, false);
        pk = __builtin_amdgcn_cvt_pk_fp8_f32(e[2], e[3], pk, true);
        *(unsigned int*)(&Eb[(size_t)(grow + r) * S_ + colBase + waveN * 64 +
                             lrow * 4]) = pk;
        partial += __shfl_xor(partial, 1);
        partial += __shfl_xor(partial, 2);
        partial += __shfl_xor(partial, 4);
        partial += __shfl_xor(partial, 8);
        if (lrow == 0) atomicAdd(&rs[grow + r], partial);
      }
    }
  }
}

// ---- wsum[k] = (1/S)·Σ_q e[q,k]/rowsum[q]; fp8 input, permuted cols -------
// dword d of a row: byte jj -> true col (d>>4)*64 + (d&15) + 16*jj.
__global__ __launch_bounds__(256) void colsum_kernel(
    const unsigned int* __restrict__ Epk, const float* __restrict__ rowsum,
    float* __restrict__ wsum) {
  const int b = blockIdx.y, q0 = blockIdx.x * 64, t = threadIdx.x;
  __shared__ float rinv[64];
  if (t < 64) rinv[t] = 1.0f / rowsum[(size_t)b * S_ + q0 + t];
  __syncthreads();
  float cs[2][4] = {{0, 0, 0, 0}, {0, 0, 0, 0}};
  const unsigned int* Eb = Epk + ((size_t)b * S_ + q0) * (S_ / 4);
  for (int q = 0; q < 64; ++q) {
    const float rv = rinv[q];
    const unsigned int* row = Eb + (size_t)q * (S_ / 4);
#pragma unroll
    for (int j = 0; j < 2; ++j) {
      const unsigned int p = row[t + 256 * j];
      f32x2 lo = __builtin_amdgcn_cvt_pk_f32_fp8(p, false);
      f32x2 hi = __builtin_amdgcn_cvt_pk_f32_fp8(p, true);
      cs[j][0] += lo[0] * rv;
      cs[j][1] += lo[1] * rv;
      cs[j][2] += hi[0] * rv;
      cs[j][3] += hi[1] * rv;
    }
  }
  const float inv = 1.0f / (float)S_;
#pragma unroll
  for (int j = 0; j < 2; ++j) {
    const int d = t + 256 * j;
    const int base = (d >> 4) * 64 + (d & 15);
#pragma unroll
    for (int jj = 0; jj < 4; ++jj)
      atomicAdd(&wsum[(size_t)b * S_ + base + 16 * jj], cs[j][jj] * inv);
  }
}

// ---- xbar[b,e] = Σ_k wsum[b,k]·xbf[b,k,e]  (bf16 x) -----------------------
__global__ __launch_bounds__(256) void xbar_kernel(
    const unsigned short* __restrict__ xbf, const float* __restrict__ wsum,
    float* __restrict__ xbar) {
  const int b = blockIdx.y, kc = blockIdx.x, t = threadIdx.x;
  float4 acc = {0.f, 0.f, 0.f, 0.f};
  for (int k0 = 0; k0 < 128; ++k0) {
    const int k = kc * 128 + k0;
    const float w = wsum[(size_t)b * S_ + k];
    const ushort4 xv =
        *(const ushort4*)(xbf + ((size_t)b * S_ + k) * E_ + t * 4);
    acc.x += w * __uint_as_float((unsigned int)xv.x << 16);
    acc.y += w * __uint_as_float((unsigned int)xv.y << 16);
    acc.z += w * __uint_as_float((unsigned int)xv.z << 16);
    acc.w += w * __uint_as_float((unsigned int)xv.w << 16);
  }
  float* xb = xbar + (size_t)b * E_ + t * 4;
  atomicAdd(&xb[0], acc.x);
  atomicAdd(&xb[1], acc.y);
  atomicAdd(&xb[2], acc.z);
  atomicAdd(&xb[3], acc.w);
}

// ---- out[b,e] += Σ_{chunk} xbar[b,c]·wv[e,c] (+bv on chunk 0) -------------
__global__ __launch_bounds__(256) void out_kernel(
    const float* __restrict__ xbar, const float* __restrict__ wv,
    const float* __restrict__ bv, float* __restrict__ out) {
  const int gid = blockIdx.x * 256 + threadIdx.x;
  const int b = gid >> 10, e = gid & 1023;
  const int c0 = blockIdx.y * 64;
  const float4* xr = (const float4*)(xbar + (size_t)b * E_) + c0;
  const float4* wr = (const float4*)(wv + (size_t)e * E_) + c0;
  float s = 0.f;
  for (int j = 0; j < 64; ++j) {
    float4 a = xr[j], w = wr[j];
    s += a.x * w.x + a.y * w.y + a.z * w.z + a.w * w.w;
  }
  if (blockIdx.y == 0) s += bv[e];
  atomicAdd(&out[gid], s);
}

extern "C" void kernel_launch(void* const* d_in, const int* in_sizes, int n_in,
                              void* d_out, int out_size, void* d_ws,
                              size_t ws_size, hipStream_t stream) {
  const float* x = (const float*)d_in[0];
  const float* wq = (const float*)d_in[1];
  const float* bq = (const float*)d_in[2];
  const float* wk = (const float*)d_in[3];
  // bk cancels in softmax
  const float* wv = (const float*)d_in[5];
  const float* bv = (const float*)d_in[6];
  float* out = (float*)d_out;

  char* ws = (char*)d_ws;
  const size_t MB = 1ull << 20;
  // xbf(64MB) | y bf16(64MB) | Ebuf fp8(64MB) | WqT(2) | WkT(2) | Mt(2)
  // | Z: g(4KB) rowsum(128KB) wsum(128KB) xbar(64KB) | vs(128KB)
  unsigned short* xbf = (unsigned short*)(ws);
  unsigned short* y = (unsigned short*)(ws + 64 * MB);
  unsigned char* Ebuf = (unsigned char*)(ws + 128 * MB);
  unsigned short* WqT = (unsigned short*)(ws + 192 * MB);
  unsigned short* WkT = (unsigned short*)(ws + 194 * MB);
  unsigned short* Mt = (unsigned short*)(ws + 196 * MB);
  float* g = (float*)(ws + 198 * MB);
  float* rowsum = g + E_;
  float* wsum = rowsum + B_ * S_;
  float* xbar = wsum + B_ * S_;
  float* vs = xbar + B_ * E_;

  hipMemsetAsync(g, 0, (size_t)(E_ + 2 * B_ * S_ + B_ * E_) * sizeof(float),
                 stream);
  hipMemsetAsync(out, 0, (size_t)B_ * E_ * sizeof(float), stream);

  gvec_kernel<<<dim3(E_ / 256, 32), 256, 0, stream>>>(wk, bq, g);
  cast_x_v_kernel<<<B_ * S_, 256, 0, stream>>>(x, g, xbf, vs);
  tcast_kernel<<<dim3(32, 32), 256, 0, stream>>>(wq, WqT);
  tcast_kernel<<<dim3(32, 32), 256, 0, stream>>>(wk, WkT);

  // Mt[e',e] = Σ_f wk[f,e']·wq[f,e]  (bf16 out)
  gemm_bt<0><<<dim3(8, 8), 256, 0, stream>>>(
      WkT, WqT, (void*)Mt, nullptr, nullptr, 1.0f, E_, E_, E_, E_, 0, 0, 0);
  // y = x·M  (bf16 out)
  gemm_bt<0><<<dim3(E_ / 128, (B_ * S_) / 128), 256, 0, stream>>>(
      xbf, Mt, (void*)y, nullptr, nullptr, 1.0f, E_, E_, E_, E_, 0, 0, 0);
  // e[b,q,k] = exp(y_q·x_k/32 + vs[b,k]) -> fp8 π-permuted; rowsum fp32
  gemm_bt<1><<<dim3(S_ / 128, S_ / 128, B_), 256, 0, stream>>>(
      y, xbf, (void*)Ebuf, vs, rowsum, 0.03125f, E_, E_, E_, S_,
      (long long)S_ * E_, (long long)S_ * E_, (long long)S_ * S_);

  colsum_kernel<<<dim3(S_ / 64, B_), 256, 0, stream>>>(
      (const unsigned int*)Ebuf, rowsum, wsum);
  xbar_kernel<<<dim3(16, B_), 256, 0, stream>>>(xbf, wsum, xbar);
  out_kernel<<<dim3(B_ * E_ / 256, 4), 256, 0, stream>>>(xbar, wv, bv, out);
}

// Round 7
// 497.944 us; speedup vs baseline: 1.1363x; 1.1363x over previous
//
#include <hip/hip_runtime.h>

// SimpleSelfAttention: B=16, S=2048, E=1024, fp32 in/out.
// out[b] = mean_q softmax(QK^T/32)·V == (Σ_k w[b,k]·x[b,k,:]) @ Wv^T + bv.
// Softmax shift-invariance: QK^T ≡ x·(Wq^T·Wk)·x^T + 1·v^T, v = x·(Wk^T·bq).
// R10 (resubmit after broker timeout): revert gemm_bt K-loop to the PROVEN
// R7 body (R8 256²/8-phase and R9 reg-staging both regressed — m97
// 2-barrier + compiler scheduling is the local optimum at K=1024). Keep
// R9's XCD swizzle (FETCH 295->164 MB, verified). New: the non-GEMM bucket
// is ~280 µs at only ~1.2 TB/s — restructure the worst offenders:
//   cast_x_v: wave-per-row, 64B/thread coalesced, shfl-only reduce.
//   xbar: 512 blocks + unroll 4.  colsum: 1024 blocks, q-chunk 32.
// Keep: fp8 π-permuted e-store, fp8 colsum, bf16 xbar, split-E out.

#define B_ 16
#define S_ 2048
#define E_ 1024

typedef __bf16 bf16x8 __attribute__((ext_vector_type(8)));
typedef float f32x4 __attribute__((ext_vector_type(4)));
typedef float f32x2 __attribute__((ext_vector_type(2)));

__device__ __forceinline__ unsigned short f2bf(float f) {
  unsigned int u = __float_as_uint(f);
  u = (u + 0x7FFFu + ((u >> 16) & 1u)) >> 16;  // RNE; finite inputs
  return (unsigned short)u;
}

// ---- g[e] = Σ_f wk[f,e]·bq[f] ---------------------------------------------
__global__ __launch_bounds__(256) void gvec_kernel(
    const float* __restrict__ wk, const float* __restrict__ bq,
    float* __restrict__ g) {
  const int e = blockIdx.x * 256 + threadIdx.x;
  const int f0 = blockIdx.y * 32;
  float acc = 0.f;
#pragma unroll
  for (int i = 0; i < 32; ++i) acc += wk[(size_t)(f0 + i) * E_ + e] * bq[f0 + i];
  atomicAdd(&g[e], acc);
}

// ---- cast x -> bf16 AND vs[row] = (x_row · g)/32 ; wave == one row --------
// R10: 4 rows/block (one wave each), 64B/thread coalesced float4 loads,
// pure shfl reduce — no LDS, no __syncthreads.
__global__ __launch_bounds__(256) void cast_x_v_kernel(
    const float* __restrict__ x, const float* __restrict__ g,
    unsigned short* __restrict__ xbf, float* __restrict__ vs) {
  const int t = threadIdx.x;
  const int row = blockIdx.x * 4 + (t >> 6);
  const int lane = t & 63;
  const float4* xr = (const float4*)(x + (size_t)row * E_);
  const float4* g4 = (const float4*)g;
  ushort4* xb4 = (ushort4*)(xbf + (size_t)row * E_);
  float p = 0.f;
#pragma unroll
  for (int j = 0; j < 4; ++j) {
    const int idx = j * 64 + lane;
    float4 v = xr[idx];
    float4 gv = g4[idx];
    ushort4 o;
    o.x = f2bf(v.x); o.y = f2bf(v.y); o.z = f2bf(v.z); o.w = f2bf(v.w);
    xb4[idx] = o;
    p += v.x * gv.x + v.y * gv.y + v.z * gv.z + v.w * gv.w;
  }
#pragma unroll
  for (int off = 32; off >= 1; off >>= 1) p += __shfl_xor(p, off);
  if (lane == 0) vs[row] = p * 0.03125f;
}

// ---- transpose-cast: dst[e,f] = bf16(src[f,e]), 1024x1024 -----------------
__global__ __launch_bounds__(256) void tcast_kernel(
    const float* __restrict__ src, unsigned short* __restrict__ dst) {
  __shared__ float tile[32][33];
  const int tx = threadIdx.x & 31, ty = threadIdx.x >> 5;
  const int f0 = blockIdx.y * 32, e0 = blockIdx.x * 32;
#pragma unroll
  for (int j = 0; j < 4; ++j)
    tile[ty + 8 * j][tx] = src[(size_t)(f0 + ty + 8 * j) * E_ + e0 + tx];
  __syncthreads();
#pragma unroll
  for (int j = 0; j < 4; ++j)
    dst[(size_t)(e0 + ty + 8 * j) * E_ + f0 + tx] = f2bf(tile[tx][ty + 8 * j]);
}

// ---- bf16 MFMA GEMM, 128x128 tile, BK=64, 4 waves, 16x16x32 MFMA ----------
// PROVEN R7 K-loop body (stage -> sync -> ds_read+MFMA interleaved -> sync;
// compiler-scheduled lgkmcnt) + R9's XCD-aware bijective block swizzle.
// MODE 0: C(bf16) = A·B^T            (Mt, y — no bias)
// MODE 1: e = exp(A·B^T·scale + vs[bz*S+col]); fp8-e4m3 π-permuted packed
//         store (dword per (row, 64-col grp): byte ni -> col grp*64+16ni+lr);
//         fp32 rowsum via 16-lane shfl + atomic.
template <int MODE>
__global__ __launch_bounds__(256, 2) void gemm_bt(
    const unsigned short* __restrict__ A, const unsigned short* __restrict__ Bm,
    void* __restrict__ Cout, const float* __restrict__ vs,
    float* __restrict__ rowsum, float scale,
    int K, int lda, int ldb, int ldc,
    long long strideA, long long strideB, long long strideC) {
  __shared__ unsigned short As[128 * 64];  // 16 KB
  __shared__ unsigned short Bs[128 * 64];  // 16 KB

  const int tid = threadIdx.x;
  const int wave = tid >> 6;
  const int lane = tid & 63;

  // XCD-aware bijective swizzle: HW sends block lin to XCD lin%8; remap so
  // XCD k works tiles [k*cpx,(k+1)*cpx) x-fastest -> per-XCD L2 locality.
  // All gemm_bt grids have nwg % 8 == 0 (64 / 2048 / 4096).
  const unsigned nwg = gridDim.x * gridDim.y * gridDim.z;
  const unsigned lin =
      blockIdx.x + gridDim.x * (blockIdx.y + gridDim.y * blockIdx.z);
  const unsigned cpx = nwg >> 3;
  const unsigned tz = (lin & 7) * cpx + (lin >> 3);
  const unsigned bxi = tz % gridDim.x;
  const unsigned rest = tz / gridDim.x;
  const unsigned byi = rest % gridDim.y;
  const unsigned bz = rest / gridDim.y;

  const unsigned short* Ab = A + (size_t)bz * strideA;
  const unsigned short* Bb = Bm + (size_t)bz * strideB;
  const int rowBase = byi * 128;
  const int colBase = bxi * 128;

  const int waveM = wave >> 1, waveN = wave & 1;
  const int lrow = lane & 15, lq = lane >> 4;

  const int rsub = lane >> 3;                   // row within 8-row chunk
  const int gOff = (((lane & 7) ^ rsub) << 3);  // swizzled source granule

  f32x4 acc[4][4];
#pragma unroll
  for (int i = 0; i < 4; ++i)
#pragma unroll
    for (int j = 0; j < 4; ++j) {
      f32x4 z = {0.f, 0.f, 0.f, 0.f};
      acc[i][j] = z;
    }

  for (int k0 = 0; k0 < K; k0 += 64) {
#pragma unroll
    for (int i = 0; i < 4; ++i) {
      const int chunk = wave * 4 + i;
      const int r = chunk * 8 + rsub;
      const unsigned short* ga = Ab + (size_t)(rowBase + r) * lda + (k0 + gOff);
      const unsigned short* gb = Bb + (size_t)(colBase + r) * ldb + (k0 + gOff);
      __builtin_amdgcn_global_load_lds(
          (const __attribute__((address_space(1))) void*)ga,
          (__attribute__((address_space(3))) void*)(&As[chunk * 512]), 16, 0, 0);
      __builtin_amdgcn_global_load_lds(
          (const __attribute__((address_space(1))) void*)gb,
          (__attribute__((address_space(3))) void*)(&Bs[chunk * 512]), 16, 0, 0);
    }
    __syncthreads();

#pragma unroll
    for (int ks = 0; ks < 2; ++ks) {
      const int gg = (((ks * 4 + lq) ^ (lrow & 7)) << 3);
      bf16x8 af[4], bfv[4];
#pragma unroll
      for (int mi = 0; mi < 4; ++mi)
        af[mi] = *(const bf16x8*)(&As[(waveM * 64 + mi * 16 + lrow) * 64 + gg]);
#pragma unroll
      for (int ni = 0; ni < 4; ++ni)
        bfv[ni] = *(const bf16x8*)(&Bs[(waveN * 64 + ni * 16 + lrow) * 64 + gg]);
#pragma unroll
      for (int mi = 0; mi < 4; ++mi)
#pragma unroll
        for (int ni = 0; ni < 4; ++ni)
          acc[mi][ni] = __builtin_amdgcn_mfma_f32_16x16x32_bf16(
              af[mi], bfv[ni], acc[mi][ni], 0, 0, 0);
    }
    __syncthreads();
  }

  // epilogue: C/D layout col=lane&15, row=(lane>>4)*4+reg  [m89-verified]
  if constexpr (MODE == 0) {
    unsigned short* Cb = (unsigned short*)Cout;
#pragma unroll
    for (int mi = 0; mi < 4; ++mi) {
      const int grow = rowBase + waveM * 64 + mi * 16 + lq * 4;
#pragma unroll
      for (int ni = 0; ni < 4; ++ni) {
        const int gcol = colBase + waveN * 64 + ni * 16 + lrow;
#pragma unroll
        for (int r = 0; r < 4; ++r)
          Cb[(size_t)(grow + r) * ldc + gcol] = f2bf(acc[mi][ni][r]);
      }
    }
  } else {
    unsigned char* Eb = (unsigned char*)Cout + (size_t)bz * strideC;
    float* rs = rowsum + (size_t)bz * S_;
    const float* vsb = vs + (size_t)bz * S_;
    float badd[4];
#pragma unroll
    for (int ni = 0; ni < 4; ++ni)
      badd[ni] = vsb[colBase + waveN * 64 + ni * 16 + lrow];
#pragma unroll
    for (int mi = 0; mi < 4; ++mi) {
      const int grow = rowBase + waveM * 64 + mi * 16 + lq * 4;
#pragma unroll
      for (int r = 0; r < 4; ++r) {
        float e[4];
        float partial = 0.f;
#pragma unroll
        for (int ni = 0; ni < 4; ++ni) {
          e[ni] = __expf(acc[mi][ni][r] * scale + badd[ni]);
          partial += e[ni];
        }
        unsigned int pk = 0;
        pk = __builtin_amdgcn_cvt_pk_fp8_f32(e[0], e[1], pk, false);
        pk = __builtin_amdgcn_cvt_pk_fp8_f32(e[2], e[3], pk, true);
        *(unsigned int*)(&Eb[(size_t)(grow + r) * S_ + colBase + waveN * 64 +
                             lrow * 4]) = pk;
        partial += __shfl_xor(partial, 1);
        partial += __shfl_xor(partial, 2);
        partial += __shfl_xor(partial, 4);
        partial += __shfl_xor(partial, 8);
        if (lrow == 0) atomicAdd(&rs[grow + r], partial);
      }
    }
  }
}

// ---- wsum[k] = (1/S)·Σ_q e[q,k]/rowsum[q]; fp8 input, permuted cols -------
// dword d of a row: byte jj -> true col (d>>4)*64 + (d&15) + 16*jj.
// R10: 1024 blocks (q-chunk 32) for 4 blocks/CU.
__global__ __launch_bounds__(256) void colsum_kernel(
    const unsigned int* __restrict__ Epk, const float* __restrict__ rowsum,
    float* __restrict__ wsum) {
  const int b = blockIdx.y, q0 = blockIdx.x * 32, t = threadIdx.x;
  __shared__ float rinv[32];
  if (t < 32) rinv[t] = 1.0f / rowsum[(size_t)b * S_ + q0 + t];
  __syncthreads();
  float cs[2][4] = {{0, 0, 0, 0}, {0, 0, 0, 0}};
  const unsigned int* Eb = Epk + ((size_t)b * S_ + q0) * (S_ / 4);
#pragma unroll 2
  for (int q = 0; q < 32; ++q) {
    const float rv = rinv[q];
    const unsigned int* row = Eb + (size_t)q * (S_ / 4);
#pragma unroll
    for (int j = 0; j < 2; ++j) {
      const unsigned int p = row[t + 256 * j];
      f32x2 lo = __builtin_amdgcn_cvt_pk_f32_fp8(p, false);
      f32x2 hi = __builtin_amdgcn_cvt_pk_f32_fp8(p, true);
      cs[j][0] += lo[0] * rv;
      cs[j][1] += lo[1] * rv;
      cs[j][2] += hi[0] * rv;
      cs[j][3] += hi[1] * rv;
    }
  }
  const float inv = 1.0f / (float)S_;
#pragma unroll
  for (int j = 0; j < 2; ++j) {
    const int d = t + 256 * j;
    const int base = (d >> 4) * 64 + (d & 15);
#pragma unroll
    for (int jj = 0; jj < 4; ++jj)
      atomicAdd(&wsum[(size_t)b * S_ + base + 16 * jj], cs[j][jj] * inv);
  }
}

// ---- xbar[b,e] = Σ_k wsum[b,k]·xbf[b,k,e]  (bf16 x) -----------------------
// R10: 512 blocks (k-chunk 64) + unroll 4 for MLP.
__global__ __launch_bounds__(256) void xbar_kernel(
    const unsigned short* __restrict__ xbf, const float* __restrict__ wsum,
    float* __restrict__ xbar) {
  const int b = blockIdx.y, kc = blockIdx.x, t = threadIdx.x;
  float4 acc = {0.f, 0.f, 0.f, 0.f};
#pragma unroll 4
  for (int k0 = 0; k0 < 64; ++k0) {
    const int k = kc * 64 + k0;
    const float w = wsum[(size_t)b * S_ + k];
    const ushort4 xv =
        *(const ushort4*)(xbf + ((size_t)b * S_ + k) * E_ + t * 4);
    acc.x += w * __uint_as_float((unsigned int)xv.x << 16);
    acc.y += w * __uint_as_float((unsigned int)xv.y << 16);
    acc.z += w * __uint_as_float((unsigned int)xv.z << 16);
    acc.w += w * __uint_as_float((unsigned int)xv.w << 16);
  }
  float* xb = xbar + (size_t)b * E_ + t * 4;
  atomicAdd(&xb[0], acc.x);
  atomicAdd(&xb[1], acc.y);
  atomicAdd(&xb[2], acc.z);
  atomicAdd(&xb[3], acc.w);
}

// ---- out[b,e] += Σ_{chunk} xbar[b,c]·wv[e,c] (+bv on chunk 0) -------------
__global__ __launch_bounds__(256) void out_kernel(
    const float* __restrict__ xbar, const float* __restrict__ wv,
    const float* __restrict__ bv, float* __restrict__ out) {
  const int gid = blockIdx.x * 256 + threadIdx.x;
  const int b = gid >> 10, e = gid & 1023;
  const int c0 = blockIdx.y * 64;
  const float4* xr = (const float4*)(xbar + (size_t)b * E_) + c0;
  const float4* wr = (const float4*)(wv + (size_t)e * E_) + c0;
  float s = 0.f;
  for (int j = 0; j < 64; ++j) {
    float4 a = xr[j], w = wr[j];
    s += a.x * w.x + a.y * w.y + a.z * w.z + a.w * w.w;
  }
  if (blockIdx.y == 0) s += bv[e];
  atomicAdd(&out[gid], s);
}

extern "C" void kernel_launch(void* const* d_in, const int* in_sizes, int n_in,
                              void* d_out, int out_size, void* d_ws,
                              size_t ws_size, hipStream_t stream) {
  const float* x = (const float*)d_in[0];
  const float* wq = (const float*)d_in[1];
  const float* bq = (const float*)d_in[2];
  const float* wk = (const float*)d_in[3];
  // bk cancels in softmax
  const float* wv = (const float*)d_in[5];
  const float* bv = (const float*)d_in[6];
  float* out = (float*)d_out;

  char* ws = (char*)d_ws;
  const size_t MB = 1ull << 20;
  // xbf(64MB) | y bf16(64MB) | Ebuf fp8(64MB) | WqT(2) | WkT(2) | Mt(2)
  // | Z: g(4KB) rowsum(128KB) wsum(128KB) xbar(64KB) | vs(128KB)
  unsigned short* xbf = (unsigned short*)(ws);
  unsigned short* y = (unsigned short*)(ws + 64 * MB);
  unsigned char* Ebuf = (unsigned char*)(ws + 128 * MB);
  unsigned short* WqT = (unsigned short*)(ws + 192 * MB);
  unsigned short* WkT = (unsigned short*)(ws + 194 * MB);
  unsigned short* Mt = (unsigned short*)(ws + 196 * MB);
  float* g = (float*)(ws + 198 * MB);
  float* rowsum = g + E_;
  float* wsum = rowsum + B_ * S_;
  float* xbar = wsum + B_ * S_;
  float* vs = xbar + B_ * E_;

  hipMemsetAsync(g, 0, (size_t)(E_ + 2 * B_ * S_ + B_ * E_) * sizeof(float),
                 stream);
  hipMemsetAsync(out, 0, (size_t)B_ * E_ * sizeof(float), stream);

  gvec_kernel<<<dim3(E_ / 256, 32), 256, 0, stream>>>(wk, bq, g);
  cast_x_v_kernel<<<B_ * S_ / 4, 256, 0, stream>>>(x, g, xbf, vs);
  tcast_kernel<<<dim3(32, 32), 256, 0, stream>>>(wq, WqT);
  tcast_kernel<<<dim3(32, 32), 256, 0, stream>>>(wk, WkT);

  // Mt[e',e] = Σ_f wk[f,e']·wq[f,e]  (bf16 out)
  gemm_bt<0><<<dim3(8, 8), 256, 0, stream>>>(
      WkT, WqT, (void*)Mt, nullptr, nullptr, 1.0f, E_, E_, E_, E_, 0, 0, 0);
  // y = x·M  (bf16 out)
  gemm_bt<0><<<dim3(E_ / 128, (B_ * S_) / 128), 256, 0, stream>>>(
      xbf, Mt, (void*)y, nullptr, nullptr, 1.0f, E_, E_, E_, E_, 0, 0, 0);
  // e[b,q,k] = exp(y_q·x_k/32 + vs[b,k]) -> fp8 π-permuted; rowsum fp32
  gemm_bt<1><<<dim3(S_ / 128, S_ / 128, B_), 256, 0, stream>>>(
      y, xbf, (void*)Ebuf, vs, rowsum, 0.03125f, E_, E_, E_, S_,
      (long long)S_ * E_, (long long)S_ * E_, (long long)S_ * S_);

  colsum_kernel<<<dim3(S_ / 32, B_), 256, 0, stream>>>(
      (const unsigned int*)Ebuf, rowsum, wsum);
  xbar_kernel<<<dim3(32, B_), 256, 0, stream>>>(xbf, wsum, xbar);
  out_kernel<<<dim3(B_ * E_ / 256, 4), 256, 0, stream>>>(xbar, wv, bv, out);
}

// Round 9
// 482.818 us; speedup vs baseline: 1.1719x; 1.0313x over previous
//
#include <hip/hip_runtime.h>

// SimpleSelfAttention: B=16, S=2048, E=1024, fp32 in/out.
// out[b] = mean_q softmax(QK^T/32)·V == (Σ_k w[b,k]·x[b,k,:]) @ Wv^T + bv.
// Softmax shift-invariance: QK^T ≡ x·(Wq^T·Wk)·x^T + 1·v^T, v = x·(Wk^T·bq).
// R11 (resubmit after broker timeout): hybrid. Clean A/B (R7 vs R10) showed
// the XCD swizzle REGRESSED the scores GEMM (141.9 -> 162.4 µs despite
// FETCH 295->170 MB): L3-fit + latency-sensitive regime — swizzle dropped.
// Ledger arithmetic (R0 vs R4) showed y at 256²/8-phase ≈ 44 µs vs ~71 at
// 128² (Mt is L2-resident -> pipeline fills). So: scores = exact R7 128²
// gemm_bt (no swizzle); y = R4-verified gemm256 8-phase; Mt = 128²;
// non-GEMM = R10 rewrites.
// Keep: fp8 π-permuted e-store, fp8 colsum, bf16 xbar, split-E out.

#define B_ 16
#define S_ 2048
#define E_ 1024

typedef __bf16 bf16x8 __attribute__((ext_vector_type(8)));
typedef float f32x4 __attribute__((ext_vector_type(4)));
typedef float f32x2 __attribute__((ext_vector_type(2)));

__device__ __forceinline__ unsigned short f2bf(float f) {
  unsigned int u = __float_as_uint(f);
  u = (u + 0x7FFFu + ((u >> 16) & 1u)) >> 16;  // RNE; finite inputs
  return (unsigned short)u;
}

// ---- g[e] = Σ_f wk[f,e]·bq[f] ---------------------------------------------
__global__ __launch_bounds__(256) void gvec_kernel(
    const float* __restrict__ wk, const float* __restrict__ bq,
    float* __restrict__ g) {
  const int e = blockIdx.x * 256 + threadIdx.x;
  const int f0 = blockIdx.y * 32;
  float acc = 0.f;
#pragma unroll
  for (int i = 0; i < 32; ++i) acc += wk[(size_t)(f0 + i) * E_ + e] * bq[f0 + i];
  atomicAdd(&g[e], acc);
}

// ---- cast x -> bf16 AND vs[row] = (x_row · g)/32 ; wave == one row --------
__global__ __launch_bounds__(256) void cast_x_v_kernel(
    const float* __restrict__ x, const float* __restrict__ g,
    unsigned short* __restrict__ xbf, float* __restrict__ vs) {
  const int t = threadIdx.x;
  const int row = blockIdx.x * 4 + (t >> 6);
  const int lane = t & 63;
  const float4* xr = (const float4*)(x + (size_t)row * E_);
  const float4* g4 = (const float4*)g;
  ushort4* xb4 = (ushort4*)(xbf + (size_t)row * E_);
  float p = 0.f;
#pragma unroll
  for (int j = 0; j < 4; ++j) {
    const int idx = j * 64 + lane;
    float4 v = xr[idx];
    float4 gv = g4[idx];
    ushort4 o;
    o.x = f2bf(v.x); o.y = f2bf(v.y); o.z = f2bf(v.z); o.w = f2bf(v.w);
    xb4[idx] = o;
    p += v.x * gv.x + v.y * gv.y + v.z * gv.z + v.w * gv.w;
  }
#pragma unroll
  for (int off = 32; off >= 1; off >>= 1) p += __shfl_xor(p, off);
  if (lane == 0) vs[row] = p * 0.03125f;
}

// ---- transpose-cast: dst[e,f] = bf16(src[f,e]), 1024x1024 -----------------
__global__ __launch_bounds__(256) void tcast_kernel(
    const float* __restrict__ src, unsigned short* __restrict__ dst) {
  __shared__ float tile[32][33];
  const int tx = threadIdx.x & 31, ty = threadIdx.x >> 5;
  const int f0 = blockIdx.y * 32, e0 = blockIdx.x * 32;
#pragma unroll
  for (int j = 0; j < 4; ++j)
    tile[ty + 8 * j][tx] = src[(size_t)(f0 + ty + 8 * j) * E_ + e0 + tx];
  __syncthreads();
#pragma unroll
  for (int j = 0; j < 4; ++j)
    dst[(size_t)(e0 + ty + 8 * j) * E_ + f0 + tx] = f2bf(tile[tx][ty + 8 * j]);
}

// ---- bf16 MFMA GEMM, 128x128 tile, BK=64, 4 waves, 16x16x32 MFMA ----------
// EXACT R7 body (proven 141.9 µs on scores). No swizzle.
// MODE 0: C(bf16) = A·B^T            (Mt — no bias)
// MODE 1: e = exp(A·B^T·scale + vs[bz*S+col]); fp8-e4m3 π-permuted packed
//         store (dword per (row, 64-col grp): byte ni -> col grp*64+16ni+lr);
//         fp32 rowsum via 16-lane shfl + atomic.
template <int MODE>
__global__ __launch_bounds__(256, 2) void gemm_bt(
    const unsigned short* __restrict__ A, const unsigned short* __restrict__ Bm,
    void* __restrict__ Cout, const float* __restrict__ vs,
    float* __restrict__ rowsum, float scale,
    int K, int lda, int ldb, int ldc,
    long long strideA, long long strideB, long long strideC) {
  __shared__ unsigned short As[128 * 64];  // 16 KB
  __shared__ unsigned short Bs[128 * 64];  // 16 KB

  const int tid = threadIdx.x;
  const int wave = tid >> 6;
  const int lane = tid & 63;
  const int bz = blockIdx.z;
  const unsigned short* Ab = A + (size_t)bz * strideA;
  const unsigned short* Bb = Bm + (size_t)bz * strideB;
  const int rowBase = blockIdx.y * 128;
  const int colBase = blockIdx.x * 128;

  const int waveM = wave >> 1, waveN = wave & 1;
  const int lrow = lane & 15, lq = lane >> 4;

  const int rsub = lane >> 3;                   // row within 8-row chunk
  const int gOff = (((lane & 7) ^ rsub) << 3);  // swizzled source granule

  f32x4 acc[4][4];
#pragma unroll
  for (int i = 0; i < 4; ++i)
#pragma unroll
    for (int j = 0; j < 4; ++j) {
      f32x4 z = {0.f, 0.f, 0.f, 0.f};
      acc[i][j] = z;
    }

  for (int k0 = 0; k0 < K; k0 += 64) {
#pragma unroll
    for (int i = 0; i < 4; ++i) {
      const int chunk = wave * 4 + i;
      const int r = chunk * 8 + rsub;
      const unsigned short* ga = Ab + (size_t)(rowBase + r) * lda + (k0 + gOff);
      const unsigned short* gb = Bb + (size_t)(colBase + r) * ldb + (k0 + gOff);
      __builtin_amdgcn_global_load_lds(
          (const __attribute__((address_space(1))) void*)ga,
          (__attribute__((address_space(3))) void*)(&As[chunk * 512]), 16, 0, 0);
      __builtin_amdgcn_global_load_lds(
          (const __attribute__((address_space(1))) void*)gb,
          (__attribute__((address_space(3))) void*)(&Bs[chunk * 512]), 16, 0, 0);
    }
    __syncthreads();

#pragma unroll
    for (int ks = 0; ks < 2; ++ks) {
      const int gg = (((ks * 4 + lq) ^ (lrow & 7)) << 3);
      bf16x8 af[4], bfv[4];
#pragma unroll
      for (int mi = 0; mi < 4; ++mi)
        af[mi] = *(const bf16x8*)(&As[(waveM * 64 + mi * 16 + lrow) * 64 + gg]);
#pragma unroll
      for (int ni = 0; ni < 4; ++ni)
        bfv[ni] = *(const bf16x8*)(&Bs[(waveN * 64 + ni * 16 + lrow) * 64 + gg]);
#pragma unroll
      for (int mi = 0; mi < 4; ++mi)
#pragma unroll
        for (int ni = 0; ni < 4; ++ni)
          acc[mi][ni] = __builtin_amdgcn_mfma_f32_16x16x32_bf16(
              af[mi], bfv[ni], acc[mi][ni], 0, 0, 0);
    }
    __syncthreads();
  }

  // epilogue: C/D layout col=lane&15, row=(lane>>4)*4+reg  [m89-verified]
  if constexpr (MODE == 0) {
    unsigned short* Cb = (unsigned short*)Cout;
#pragma unroll
    for (int mi = 0; mi < 4; ++mi) {
      const int grow = rowBase + waveM * 64 + mi * 16 + lq * 4;
#pragma unroll
      for (int ni = 0; ni < 4; ++ni) {
        const int gcol = colBase + waveN * 64 + ni * 16 + lrow;
#pragma unroll
        for (int r = 0; r < 4; ++r)
          Cb[(size_t)(grow + r) * ldc + gcol] = f2bf(acc[mi][ni][r]);
      }
    }
  } else {
    unsigned char* Eb = (unsigned char*)Cout + (size_t)bz * strideC;
    float* rs = rowsum + (size_t)bz * S_;
    const float* vsb = vs + (size_t)bz * S_;
    float badd[4];
#pragma unroll
    for (int ni = 0; ni < 4; ++ni)
      badd[ni] = vsb[colBase + waveN * 64 + ni * 16 + lrow];
#pragma unroll
    for (int mi = 0; mi < 4; ++mi) {
      const int grow = rowBase + waveM * 64 + mi * 16 + lq * 4;
#pragma unroll
      for (int r = 0; r < 4; ++r) {
        float e[4];
        float partial = 0.f;
#pragma unroll
        for (int ni = 0; ni < 4; ++ni) {
          e[ni] = __expf(acc[mi][ni][r] * scale + badd[ni]);
          partial += e[ni];
        }
        unsigned int pk = 0;
        pk = __builtin_amdgcn_cvt_pk_fp8_f32(e[0], e[1], pk, false);
        pk = __builtin_amdgcn_cvt_pk_fp8_f32(e[2], e[3], pk, true);
        *(unsigned int*)(&Eb[(size_t)(grow + r) * S_ + colBase + waveN * 64 +
                             lrow * 4]) = pk;
        partial += __shfl_xor(partial, 1);
        partial += __shfl_xor(partial, 2);
        partial += __shfl_xor(partial, 4);
        partial += __shfl_xor(partial, 8);
        if (lrow == 0) atomicAdd(&rs[grow + r], partial);
      }
    }
  }
}

// ---- 256x256 tile, BK=64, 8 waves, 8-phase counted-vmcnt (R4-verified) ----
// Used ONLY for y = x·M: Mt (2 MB) is L2-resident on every XCD, so the deep
// pipeline's B-loads are low-latency hits and the schedule fills (y @256² ≈
// 44 µs vs ~71 @128², from the R0/R4 ledger). MODE 0 only.
template <int MODE>
__global__ __launch_bounds__(512, 2) void gemm256(
    const unsigned short* __restrict__ A, const unsigned short* __restrict__ Bm,
    void* __restrict__ Cout, const float* __restrict__ vs,
    float* __restrict__ rowsum, float scale, int ldc,
    long long strideA, long long strideB, long long strideC) {
  extern __shared__ __align__(16) unsigned short lds[];  // 128 KiB
  const int tid = threadIdx.x;
  const int wave = tid >> 6;
  const int lane = tid & 63;
  const int waveM = wave >> 2, waveN = wave & 3;  // 2M x 4N
  const int lrow = lane & 15, lq = lane >> 4;
  const int bz = blockIdx.z;
  const int rowBase = blockIdx.y * 256;
  const int colBase = blockIdx.x * 256;
  const unsigned short* Ab = A + (size_t)bz * strideA;
  const unsigned short* Bb = Bm + (size_t)bz * strideB;

  const int rsub = lane >> 3;
  const int gsw = ((lane & 7) ^ rsub) << 3;
  const unsigned short* Ag =
      Ab + (size_t)(rowBase + wave * 8 + rsub) * E_ + gsw;
  const unsigned short* Bg =
      Bb + (size_t)(colBase + (wave >> 2) * 64 + (wave & 3) * 8 + rsub) * E_ + gsw;
  const int ALo = wave * 512;
  const int BLo = (wave >> 2) * 4096 + (wave & 3) * 512;

#define STG(gp, lo)                                             \
  __builtin_amdgcn_global_load_lds(                             \
      (const __attribute__((address_space(1))) void*)(gp),      \
      (__attribute__((address_space(3))) void*)(lds + (lo)), 16, 0, 0)
#define STG_A0(ko, q)                                   \
  do {                                                  \
    STG(Ag + (ko), (q) * 16384 + ALo);                  \
    STG(Ag + (ko) + 131072, (q) * 16384 + ALo + 8192);  \
  } while (0)
#define STG_A1(ko, q)                                   \
  do {                                                  \
    STG(Ag + (ko) + 65536, (q) * 16384 + ALo + 4096);   \
    STG(Ag + (ko) + 196608, (q) * 16384 + ALo + 12288); \
  } while (0)
#define STG_B0(ko, q)                                            \
  do {                                                           \
    STG(Bg + (ko), 32768 + (q) * 16384 + BLo);                   \
    STG(Bg + (ko) + 131072, 32768 + (q) * 16384 + BLo + 8192);   \
  } while (0)
#define STG_B1(ko, q)                                            \
  do {                                                           \
    STG(Bg + (ko) + 32768, 32768 + (q) * 16384 + BLo + 2048);    \
    STG(Bg + (ko) + 163840, 32768 + (q) * 16384 + BLo + 10240);  \
  } while (0)

  f32x4 acc[8][4];
#pragma unroll
  for (int i = 0; i < 8; ++i)
#pragma unroll
    for (int j = 0; j < 4; ++j) {
      f32x4 z = {0.f, 0.f, 0.f, 0.f};
      acc[i][j] = z;
    }

  STG_A0(0, 0); STG_B0(0, 0); STG_B1(0, 0); STG_A1(0, 0);
  STG_A0(64, 1); STG_B0(64, 1); STG_B1(64, 1); STG_A1(64, 1);
  asm volatile("s_waitcnt vmcnt(8)" ::: "memory");
  __builtin_amdgcn_s_barrier();

  const int rowA = (waveM * 128 + lrow) * 64;
  const int rowB = (waveN * 64 + lrow) * 64;
  const int g0 = (lq ^ (lrow & 7)) * 8;
  const int g1 = ((4 | lq) ^ (lrow & 7)) * 8;

  bf16x8 a[4][2], b0[2][2], b1[2][2];

#pragma unroll 2
  for (int t = 0; t < 16; ++t) {
    const int q = t & 1;
    const unsigned short* At = lds + q * 16384;
    const unsigned short* Bt = lds + 32768 + q * 16384;
    const int ko = t * 64 + 128;
    const bool st = (t < 14);

    // p0: read A mi0-3 + B ni0-1; MFMA (miH0, niH0)
#pragma unroll
    for (int mi = 0; mi < 4; ++mi) {
      a[mi][0] = *(const bf16x8*)(At + rowA + mi * 1024 + g0);
      a[mi][1] = *(const bf16x8*)(At + rowA + mi * 1024 + g1);
    }
#pragma unroll
    for (int ni = 0; ni < 2; ++ni) {
      b0[ni][0] = *(const bf16x8*)(Bt + rowB + ni * 1024 + g0);
      b0[ni][1] = *(const bf16x8*)(Bt + rowB + ni * 1024 + g1);
    }
    __builtin_amdgcn_s_barrier();
    asm volatile("s_waitcnt lgkmcnt(0)" ::: "memory");
    __builtin_amdgcn_s_setprio(1);
#pragma unroll
    for (int mi = 0; mi < 4; ++mi)
#pragma unroll
      for (int ni = 0; ni < 2; ++ni) {
        acc[mi][ni] = __builtin_amdgcn_mfma_f32_16x16x32_bf16(
            a[mi][0], b0[ni][0], acc[mi][ni], 0, 0, 0);
        acc[mi][ni] = __builtin_amdgcn_mfma_f32_16x16x32_bf16(
            a[mi][1], b0[ni][1], acc[mi][ni], 0, 0, 0);
      }
    __builtin_amdgcn_s_setprio(0);
    __builtin_amdgcn_s_barrier();

    // p1: read B ni2-3; stage A-miH0(t+2); MFMA (miH0,niH1)
#pragma unroll
    for (int ni = 0; ni < 2; ++ni) {
      b1[ni][0] = *(const bf16x8*)(Bt + rowB + (ni + 2) * 1024 + g0);
      b1[ni][1] = *(const bf16x8*)(Bt + rowB + (ni + 2) * 1024 + g1);
    }
    if (st) STG_A0(ko, q);
    __builtin_amdgcn_s_barrier();
    asm volatile("s_waitcnt lgkmcnt(0)" ::: "memory");
    __builtin_amdgcn_s_setprio(1);
#pragma unroll
    for (int mi = 0; mi < 4; ++mi)
#pragma unroll
      for (int ni = 0; ni < 2; ++ni) {
        acc[mi][ni + 2] = __builtin_amdgcn_mfma_f32_16x16x32_bf16(
            a[mi][0], b1[ni][0], acc[mi][ni + 2], 0, 0, 0);
        acc[mi][ni + 2] = __builtin_amdgcn_mfma_f32_16x16x32_bf16(
            a[mi][1], b1[ni][1], acc[mi][ni + 2], 0, 0, 0);
      }
    __builtin_amdgcn_s_setprio(0);
    __builtin_amdgcn_s_barrier();

    // p2: read A mi4-7; stage B-niH0(t+2); MFMA (miH1,niH1)
#pragma unroll
    for (int mi = 0; mi < 4; ++mi) {
      a[mi][0] = *(const bf16x8*)(At + rowA + (mi + 4) * 1024 + g0);
      a[mi][1] = *(const bf16x8*)(At + rowA + (mi + 4) * 1024 + g1);
    }
    if (st) STG_B0(ko, q);
    __builtin_amdgcn_s_barrier();
    asm volatile("s_waitcnt lgkmcnt(0)" ::: "memory");
    __builtin_amdgcn_s_setprio(1);
#pragma unroll
    for (int mi = 0; mi < 4; ++mi)
#pragma unroll
      for (int ni = 0; ni < 2; ++ni) {
        acc[mi + 4][ni + 2] = __builtin_amdgcn_mfma_f32_16x16x32_bf16(
            a[mi][0], b1[ni][0], acc[mi + 4][ni + 2], 0, 0, 0);
        acc[mi + 4][ni + 2] = __builtin_amdgcn_mfma_f32_16x16x32_bf16(
            a[mi][1], b1[ni][1], acc[mi + 4][ni + 2], 0, 0, 0);
      }
    __builtin_amdgcn_s_setprio(0);
    __builtin_amdgcn_s_barrier();

    // p3: stage B-niH1 + A-miH1; MFMA (miH1,niH0); counted vmcnt
    if (st) { STG_B1(ko, q); STG_A1(ko, q); }
    __builtin_amdgcn_s_barrier();
    __builtin_amdgcn_s_setprio(1);
#pragma unroll
    for (int mi = 0; mi < 4; ++mi)
#pragma unroll
      for (int ni = 0; ni < 2; ++ni) {
        acc[mi + 4][ni] = __builtin_amdgcn_mfma_f32_16x16x32_bf16(
            a[mi][0], b0[ni][0], acc[mi + 4][ni], 0, 0, 0);
        acc[mi + 4][ni] = __builtin_amdgcn_mfma_f32_16x16x32_bf16(
            a[mi][1], b0[ni][1], acc[mi + 4][ni], 0, 0, 0);
      }
    __builtin_amdgcn_s_setprio(0);
    if (st)
      asm volatile("s_waitcnt vmcnt(8)" ::: "memory");
    else
      asm volatile("s_waitcnt vmcnt(0)" ::: "memory");
    __builtin_amdgcn_s_barrier();
  }
#undef STG_B1
#undef STG_B0
#undef STG_A1
#undef STG_A0
#undef STG

  if constexpr (MODE == 0) {
    unsigned short* Cb = (unsigned short*)Cout;
#pragma unroll
    for (int mi = 0; mi < 8; ++mi) {
      const int grow = rowBase + waveM * 128 + mi * 16 + lq * 4;
#pragma unroll
      for (int ni = 0; ni < 4; ++ni) {
        const int gcol = colBase + waveN * 64 + ni * 16 + lrow;
#pragma unroll
        for (int r = 0; r < 4; ++r)
          Cb[(size_t)(grow + r) * ldc + gcol] = f2bf(acc[mi][ni][r]);
      }
    }
  }
}

// ---- wsum[k] = (1/S)·Σ_q e[q,k]/rowsum[q]; fp8 input, permuted cols -------
__global__ __launch_bounds__(256) void colsum_kernel(
    const unsigned int* __restrict__ Epk, const float* __restrict__ rowsum,
    float* __restrict__ wsum) {
  const int b = blockIdx.y, q0 = blockIdx.x * 32, t = threadIdx.x;
  __shared__ float rinv[32];
  if (t < 32) rinv[t] = 1.0f / rowsum[(size_t)b * S_ + q0 + t];
  __syncthreads();
  float cs[2][4] = {{0, 0, 0, 0}, {0, 0, 0, 0}};
  const unsigned int* Eb = Epk + ((size_t)b * S_ + q0) * (S_ / 4);
#pragma unroll 2
  for (int q = 0; q < 32; ++q) {
    const float rv = rinv[q];
    const unsigned int* row = Eb + (size_t)q * (S_ / 4);
#pragma unroll
    for (int j = 0; j < 2; ++j) {
      const unsigned int p = row[t + 256 * j];
      f32x2 lo = __builtin_amdgcn_cvt_pk_f32_fp8(p, false);
      f32x2 hi = __builtin_amdgcn_cvt_pk_f32_fp8(p, true);
      cs[j][0] += lo[0] * rv;
      cs[j][1] += lo[1] * rv;
      cs[j][2] += hi[0] * rv;
      cs[j][3] += hi[1] * rv;
    }
  }
  const float inv = 1.0f / (float)S_;
#pragma unroll
  for (int j = 0; j < 2; ++j) {
    const int d = t + 256 * j;
    const int base = (d >> 4) * 64 + (d & 15);
#pragma unroll
    for (int jj = 0; jj < 4; ++jj)
      atomicAdd(&wsum[(size_t)b * S_ + base + 16 * jj], cs[j][jj] * inv);
  }
}

// ---- xbar[b,e] = Σ_k wsum[b,k]·xbf[b,k,e]  (bf16 x) -----------------------
__global__ __launch_bounds__(256) void xbar_kernel(
    const unsigned short* __restrict__ xbf, const float* __restrict__ wsum,
    float* __restrict__ xbar) {
  const int b = blockIdx.y, kc = blockIdx.x, t = threadIdx.x;
  float4 acc = {0.f, 0.f, 0.f, 0.f};
#pragma unroll 4
  for (int k0 = 0; k0 < 64; ++k0) {
    const int k = kc * 64 + k0;
    const float w = wsum[(size_t)b * S_ + k];
    const ushort4 xv =
        *(const ushort4*)(xbf + ((size_t)b * S_ + k) * E_ + t * 4);
    acc.x += w * __uint_as_float((unsigned int)xv.x << 16);
    acc.y += w * __uint_as_float((unsigned int)xv.y << 16);
    acc.z += w * __uint_as_float((unsigned int)xv.z << 16);
    acc.w += w * __uint_as_float((unsigned int)xv.w << 16);
  }
  float* xb = xbar + (size_t)b * E_ + t * 4;
  atomicAdd(&xb[0], acc.x);
  atomicAdd(&xb[1], acc.y);
  atomicAdd(&xb[2], acc.z);
  atomicAdd(&xb[3], acc.w);
}

// ---- out[b,e] += Σ_{chunk} xbar[b,c]·wv[e,c] (+bv on chunk 0) -------------
__global__ __launch_bounds__(256) void out_kernel(
    const float* __restrict__ xbar, const float* __restrict__ wv,
    const float* __restrict__ bv, float* __restrict__ out) {
  const int gid = blockIdx.x * 256 + threadIdx.x;
  const int b = gid >> 10, e = gid & 1023;
  const int c0 = blockIdx.y * 64;
  const float4* xr = (const float4*)(xbar + (size_t)b * E_) + c0;
  const float4* wr = (const float4*)(wv + (size_t)e * E_) + c0;
  float s = 0.f;
  for (int j = 0; j < 64; ++j) {
    float4 a = xr[j], w = wr[j];
    s += a.x * w.x + a.y * w.y + a.z * w.z + a.w * w.w;
  }
  if (blockIdx.y == 0) s += bv[e];
  atomicAdd(&out[gid], s);
}

extern "C" void kernel_launch(void* const* d_in, const int* in_sizes, int n_in,
                              void* d_out, int out_size, void* d_ws,
                              size_t ws_size, hipStream_t stream) {
  const float* x = (const float*)d_in[0];
  const float* wq = (const float*)d_in[1];
  const float* bq = (const float*)d_in[2];
  const float* wk = (const float*)d_in[3];
  // bk cancels in softmax
  const float* wv = (const float*)d_in[5];
  const float* bv = (const float*)d_in[6];
  float* out = (float*)d_out;

  char* ws = (char*)d_ws;
  const size_t MB = 1ull << 20;
  // xbf(64MB) | y bf16(64MB) | Ebuf fp8(64MB) | WqT(2) | WkT(2) | Mt(2)
  // | Z: g(4KB) rowsum(128KB) wsum(128KB) xbar(64KB) | vs(128KB)
  unsigned short* xbf = (unsigned short*)(ws);
  unsigned short* y = (unsigned short*)(ws + 64 * MB);
  unsigned char* Ebuf = (unsigned char*)(ws + 128 * MB);
  unsigned short* WqT = (unsigned short*)(ws + 192 * MB);
  unsigned short* WkT = (unsigned short*)(ws + 194 * MB);
  unsigned short* Mt = (unsigned short*)(ws + 196 * MB);
  float* g = (float*)(ws + 198 * MB);
  float* rowsum = g + E_;
  float* wsum = rowsum + B_ * S_;
  float* xbar = wsum + B_ * S_;
  float* vs = xbar + B_ * E_;

  // 128 KiB dynamic LDS opt-in for the y 256² kernel
  hipFuncSetAttribute(reinterpret_cast<const void*>(gemm256<0>),
                      hipFuncAttributeMaxDynamicSharedMemorySize, 131072);

  hipMemsetAsync(g, 0, (size_t)(E_ + 2 * B_ * S_ + B_ * E_) * sizeof(float),
                 stream);
  hipMemsetAsync(out, 0, (size_t)B_ * E_ * sizeof(float), stream);

  gvec_kernel<<<dim3(E_ / 256, 32), 256, 0, stream>>>(wk, bq, g);
  cast_x_v_kernel<<<B_ * S_ / 4, 256, 0, stream>>>(x, g, xbf, vs);
  tcast_kernel<<<dim3(32, 32), 256, 0, stream>>>(wq, WqT);
  tcast_kernel<<<dim3(32, 32), 256, 0, stream>>>(wk, WkT);

  // Mt[e',e] = Σ_f wk[f,e']·wq[f,e]  (bf16 out) — 128², no swizzle
  gemm_bt<0><<<dim3(8, 8), 256, 0, stream>>>(
      WkT, WqT, (void*)Mt, nullptr, nullptr, 1.0f, E_, E_, E_, E_, 0, 0, 0);
  // y = x·M  (bf16 out) — 256² 8-phase (Mt L2-resident => pipeline fills)
  gemm256<0><<<dim3(E_ / 256, (B_ * S_) / 256), 512, 131072, stream>>>(
      xbf, Mt, (void*)y, nullptr, nullptr, 1.0f, E_, 0, 0, 0);
  // e[b,q,k] = exp(y_q·x_k/32 + vs[b,k]) -> fp8 π-permuted; rowsum fp32
  // 128² proven body, no swizzle (R7 = 141.9 µs)
  gemm_bt<1><<<dim3(S_ / 128, S_ / 128, B_), 256, 0, stream>>>(
      y, xbf, (void*)Ebuf, vs, rowsum, 0.03125f, E_, E_, E_, S_,
      (long long)S_ * E_, (long long)S_ * E_, (long long)S_ * S_);

  colsum_kernel<<<dim3(S_ / 32, B_), 256, 0, stream>>>(
      (const unsigned int*)Ebuf, rowsum, wsum);
  xbar_kernel<<<dim3(32, B_), 256, 0, stream>>>(xbf, wsum, xbar);
  out_kernel<<<dim3(B_ * E_ / 256, 4), 256, 0, stream>>>(xbar, wv, bv, out);
}

// Round 13
// 465.984 us; speedup vs baseline: 1.2142x; 1.0361x over previous
//
#include <hip/hip_runtime.h>

// SimpleSelfAttention: B=16, S=2048, E=1024, fp32 in/out.
// out[b] = mean_q softmax(QK^T/32)·V == (Σ_k w[b,k]·x[b,k,:]) @ Wv^T + bv.
// Softmax shift-invariance: QK^T ≡ x·(Wq^T·Wk)·x^T + 1·v^T, v = x·(Wk^T·bq).
// R12 (3rd resubmit; repeated broker/container failures): ledger fit across
// R0/R4/R11 shows the R10 non-GEMM rewrites cost +19 µs (doubled atomics in
// colsum/xbar). Revert cast_x_v/colsum/xbar to the R0 originals (verified
// in both 490.9 and 479.96 runs). Keep the best GEMM config: scores = R7
// 128² gemm_bt unswizzled (142 µs, reproduced exactly in R11); y = 256²
// 8-phase gemm256 (y256 = y128 − 27.6 µs, d-independent ledger estimate);
// Mt = 128². This is "R0 + y upgraded".
// Keep: fp8 π-permuted e-store, fp8 colsum, bf16 xbar, split-E out.

#define B_ 16
#define S_ 2048
#define E_ 1024

typedef __bf16 bf16x8 __attribute__((ext_vector_type(8)));
typedef float f32x4 __attribute__((ext_vector_type(4)));
typedef float f32x2 __attribute__((ext_vector_type(2)));

__device__ __forceinline__ unsigned short f2bf(float f) {
  unsigned int u = __float_as_uint(f);
  u = (u + 0x7FFFu + ((u >> 16) & 1u)) >> 16;  // RNE; finite inputs
  return (unsigned short)u;
}

// ---- g[e] = Σ_f wk[f,e]·bq[f] ---------------------------------------------
__global__ __launch_bounds__(256) void gvec_kernel(
    const float* __restrict__ wk, const float* __restrict__ bq,
    float* __restrict__ g) {
  const int e = blockIdx.x * 256 + threadIdx.x;
  const int f0 = blockIdx.y * 32;
  float acc = 0.f;
#pragma unroll
  for (int i = 0; i < 32; ++i) acc += wk[(size_t)(f0 + i) * E_ + e] * bq[f0 + i];
  atomicAdd(&g[e], acc);
}

// ---- cast x -> bf16 AND vs[row] = (x_row · g)/32 ; block == one row -------
// R0 original (verified in 490.9 / 479.96 runs).
__global__ __launch_bounds__(256) void cast_x_v_kernel(
    const float* __restrict__ x, const float* __restrict__ g,
    unsigned short* __restrict__ xbf, float* __restrict__ vs) {
  const int row = blockIdx.x, t = threadIdx.x;
  const size_t i = (size_t)row * E_ + t * 4;
  float4 v = *(const float4*)(x + i);
  float4 gv = *(const float4*)(g + t * 4);
  ushort4 o;
  o.x = f2bf(v.x); o.y = f2bf(v.y); o.z = f2bf(v.z); o.w = f2bf(v.w);
  *(ushort4*)(xbf + i) = o;
  float p = v.x * gv.x + v.y * gv.y + v.z * gv.z + v.w * gv.w;
#pragma unroll
  for (int off = 32; off >= 1; off >>= 1) p += __shfl_xor(p, off);
  __shared__ float wsp[4];
  if ((t & 63) == 0) wsp[t >> 6] = p;
  __syncthreads();
  if (t == 0) vs[row] = (wsp[0] + wsp[1] + wsp[2] + wsp[3]) * 0.03125f;
}

// ---- transpose-cast: dst[e,f] = bf16(src[f,e]), 1024x1024 -----------------
__global__ __launch_bounds__(256) void tcast_kernel(
    const float* __restrict__ src, unsigned short* __restrict__ dst) {
  __shared__ float tile[32][33];
  const int tx = threadIdx.x & 31, ty = threadIdx.x >> 5;
  const int f0 = blockIdx.y * 32, e0 = blockIdx.x * 32;
#pragma unroll
  for (int j = 0; j < 4; ++j)
    tile[ty + 8 * j][tx] = src[(size_t)(f0 + ty + 8 * j) * E_ + e0 + tx];
  __syncthreads();
#pragma unroll
  for (int j = 0; j < 4; ++j)
    dst[(size_t)(e0 + ty + 8 * j) * E_ + f0 + tx] = f2bf(tile[tx][ty + 8 * j]);
}

// ---- bf16 MFMA GEMM, 128x128 tile, BK=64, 4 waves, 16x16x32 MFMA ----------
// EXACT R7 body (141.9 µs on scores; reproduced 142.3 in R11). No swizzle.
// MODE 0: C(bf16) = A·B^T            (Mt — no bias)
// MODE 1: e = exp(A·B^T·scale + vs[bz*S+col]); fp8-e4m3 π-permuted packed
//         store (dword per (row, 64-col grp): byte ni -> col grp*64+16ni+lr);
//         fp32 rowsum via 16-lane shfl + atomic.
template <int MODE>
__global__ __launch_bounds__(256, 2) void gemm_bt(
    const unsigned short* __restrict__ A, const unsigned short* __restrict__ Bm,
    void* __restrict__ Cout, const float* __restrict__ vs,
    float* __restrict__ rowsum, float scale,
    int K, int lda, int ldb, int ldc,
    long long strideA, long long strideB, long long strideC) {
  __shared__ unsigned short As[128 * 64];  // 16 KB
  __shared__ unsigned short Bs[128 * 64];  // 16 KB

  const int tid = threadIdx.x;
  const int wave = tid >> 6;
  const int lane = tid & 63;
  const int bz = blockIdx.z;
  const unsigned short* Ab = A + (size_t)bz * strideA;
  const unsigned short* Bb = Bm + (size_t)bz * strideB;
  const int rowBase = blockIdx.y * 128;
  const int colBase = blockIdx.x * 128;

  const int waveM = wave >> 1, waveN = wave & 1;
  const int lrow = lane & 15, lq = lane >> 4;

  const int rsub = lane >> 3;                   // row within 8-row chunk
  const int gOff = (((lane & 7) ^ rsub) << 3);  // swizzled source granule

  f32x4 acc[4][4];
#pragma unroll
  for (int i = 0; i < 4; ++i)
#pragma unroll
    for (int j = 0; j < 4; ++j) {
      f32x4 z = {0.f, 0.f, 0.f, 0.f};
      acc[i][j] = z;
    }

  for (int k0 = 0; k0 < K; k0 += 64) {
#pragma unroll
    for (int i = 0; i < 4; ++i) {
      const int chunk = wave * 4 + i;
      const int r = chunk * 8 + rsub;
      const unsigned short* ga = Ab + (size_t)(rowBase + r) * lda + (k0 + gOff);
      const unsigned short* gb = Bb + (size_t)(colBase + r) * ldb + (k0 + gOff);
      __builtin_amdgcn_global_load_lds(
          (const __attribute__((address_space(1))) void*)ga,
          (__attribute__((address_space(3))) void*)(&As[chunk * 512]), 16, 0, 0);
      __builtin_amdgcn_global_load_lds(
          (const __attribute__((address_space(1))) void*)gb,
          (__attribute__((address_space(3))) void*)(&Bs[chunk * 512]), 16, 0, 0);
    }
    __syncthreads();

#pragma unroll
    for (int ks = 0; ks < 2; ++ks) {
      const int gg = (((ks * 4 + lq) ^ (lrow & 7)) << 3);
      bf16x8 af[4], bfv[4];
#pragma unroll
      for (int mi = 0; mi < 4; ++mi)
        af[mi] = *(const bf16x8*)(&As[(waveM * 64 + mi * 16 + lrow) * 64 + gg]);
#pragma unroll
      for (int ni = 0; ni < 4; ++ni)
        bfv[ni] = *(const bf16x8*)(&Bs[(waveN * 64 + ni * 16 + lrow) * 64 + gg]);
#pragma unroll
      for (int mi = 0; mi < 4; ++mi)
#pragma unroll
        for (int ni = 0; ni < 4; ++ni)
          acc[mi][ni] = __builtin_amdgcn_mfma_f32_16x16x32_bf16(
              af[mi], bfv[ni], acc[mi][ni], 0, 0, 0);
    }
    __syncthreads();
  }

  // epilogue: C/D layout col=lane&15, row=(lane>>4)*4+reg  [m89-verified]
  if constexpr (MODE == 0) {
    unsigned short* Cb = (unsigned short*)Cout;
#pragma unroll
    for (int mi = 0; mi < 4; ++mi) {
      const int grow = rowBase + waveM * 64 + mi * 16 + lq * 4;
#pragma unroll
      for (int ni = 0; ni < 4; ++ni) {
        const int gcol = colBase + waveN * 64 + ni * 16 + lrow;
#pragma unroll
        for (int r = 0; r < 4; ++r)
          Cb[(size_t)(grow + r) * ldc + gcol] = f2bf(acc[mi][ni][r]);
      }
    }
  } else {
    unsigned char* Eb = (unsigned char*)Cout + (size_t)bz * strideC;
    float* rs = rowsum + (size_t)bz * S_;
    const float* vsb = vs + (size_t)bz * S_;
    float badd[4];
#pragma unroll
    for (int ni = 0; ni < 4; ++ni)
      badd[ni] = vsb[colBase + waveN * 64 + ni * 16 + lrow];
#pragma unroll
    for (int mi = 0; mi < 4; ++mi) {
      const int grow = rowBase + waveM * 64 + mi * 16 + lq * 4;
#pragma unroll
      for (int r = 0; r < 4; ++r) {
        float e[4];
        float partial = 0.f;
#pragma unroll
        for (int ni = 0; ni < 4; ++ni) {
          e[ni] = __expf(acc[mi][ni][r] * scale + badd[ni]);
          partial += e[ni];
        }
        unsigned int pk = 0;
        pk = __builtin_amdgcn_cvt_pk_fp8_f32(e[0], e[1], pk, false);
        pk = __builtin_amdgcn_cvt_pk_fp8_f32(e[2], e[3], pk, true);
        *(unsigned int*)(&Eb[(size_t)(grow + r) * S_ + colBase + waveN * 64 +
                             lrow * 4]) = pk;
        partial += __shfl_xor(partial, 1);
        partial += __shfl_xor(partial, 2);
        partial += __shfl_xor(partial, 4);
        partial += __shfl_xor(partial, 8);
        if (lrow == 0) atomicAdd(&rs[grow + r], partial);
      }
    }
  }
}

// ---- 256x256 tile, BK=64, 8 waves, 8-phase counted-vmcnt (R4-verified) ----
// Used ONLY for y = x·M: Mt (2 MB) is L2-resident on every XCD, so the deep
// pipeline's B-loads are low-latency hits and the schedule fills (y @256² ≈
// 44 µs vs ~71 @128², from the R0/R4 ledger). MODE 0 only.
template <int MODE>
__global__ __launch_bounds__(512, 2) void gemm256(
    const unsigned short* __restrict__ A, const unsigned short* __restrict__ Bm,
    void* __restrict__ Cout, const float* __restrict__ vs,
    float* __restrict__ rowsum, float scale, int ldc,
    long long strideA, long long strideB, long long strideC) {
  extern __shared__ __align__(16) unsigned short lds[];  // 128 KiB
  const int tid = threadIdx.x;
  const int wave = tid >> 6;
  const int lane = tid & 63;
  const int waveM = wave >> 2, waveN = wave & 3;  // 2M x 4N
  const int lrow = lane & 15, lq = lane >> 4;
  const int bz = blockIdx.z;
  const int rowBase = blockIdx.y * 256;
  const int colBase = blockIdx.x * 256;
  const unsigned short* Ab = A + (size_t)bz * strideA;
  const unsigned short* Bb = Bm + (size_t)bz * strideB;

  const int rsub = lane >> 3;
  const int gsw = ((lane & 7) ^ rsub) << 3;
  const unsigned short* Ag =
      Ab + (size_t)(rowBase + wave * 8 + rsub) * E_ + gsw;
  const unsigned short* Bg =
      Bb + (size_t)(colBase + (wave >> 2) * 64 + (wave & 3) * 8 + rsub) * E_ + gsw;
  const int ALo = wave * 512;
  const int BLo = (wave >> 2) * 4096 + (wave & 3) * 512;

#define STG(gp, lo)                                             \
  __builtin_amdgcn_global_load_lds(                             \
      (const __attribute__((address_space(1))) void*)(gp),      \
      (__attribute__((address_space(3))) void*)(lds + (lo)), 16, 0, 0)
#define STG_A0(ko, q)                                   \
  do {                                                  \
    STG(Ag + (ko), (q) * 16384 + ALo);                  \
    STG(Ag + (ko) + 131072, (q) * 16384 + ALo + 8192);  \
  } while (0)
#define STG_A1(ko, q)                                   \
  do {                                                  \
    STG(Ag + (ko) + 65536, (q) * 16384 + ALo + 4096);   \
    STG(Ag + (ko) + 196608, (q) * 16384 + ALo + 12288); \
  } while (0)
#define STG_B0(ko, q)                                            \
  do {                                                           \
    STG(Bg + (ko), 32768 + (q) * 16384 + BLo);                   \
    STG(Bg + (ko) + 131072, 32768 + (q) * 16384 + BLo + 8192);   \
  } while (0)
#define STG_B1(ko, q)                                            \
  do {                                                           \
    STG(Bg + (ko) + 32768, 32768 + (q) * 16384 + BLo + 2048);    \
    STG(Bg + (ko) + 163840, 32768 + (q) * 16384 + BLo + 10240);  \
  } while (0)

  f32x4 acc[8][4];
#pragma unroll
  for (int i = 0; i < 8; ++i)
#pragma unroll
    for (int j = 0; j < 4; ++j) {
      f32x4 z = {0.f, 0.f, 0.f, 0.f};
      acc[i][j] = z;
    }

  STG_A0(0, 0); STG_B0(0, 0); STG_B1(0, 0); STG_A1(0, 0);
  STG_A0(64, 1); STG_B0(64, 1); STG_B1(64, 1); STG_A1(64, 1);
  asm volatile("s_waitcnt vmcnt(8)" ::: "memory");
  __builtin_amdgcn_s_barrier();

  const int rowA = (waveM * 128 + lrow) * 64;
  const int rowB = (waveN * 64 + lrow) * 64;
  const int g0 = (lq ^ (lrow & 7)) * 8;
  const int g1 = ((4 | lq) ^ (lrow & 7)) * 8;

  bf16x8 a[4][2], b0[2][2], b1[2][2];

#pragma unroll 2
  for (int t = 0; t < 16; ++t) {
    const int q = t & 1;
    const unsigned short* At = lds + q * 16384;
    const unsigned short* Bt = lds + 32768 + q * 16384;
    const int ko = t * 64 + 128;
    const bool st = (t < 14);

    // p0: read A mi0-3 + B ni0-1; MFMA (miH0, niH0)
#pragma unroll
    for (int mi = 0; mi < 4; ++mi) {
      a[mi][0] = *(const bf16x8*)(At + rowA + mi * 1024 + g0);
      a[mi][1] = *(const bf16x8*)(At + rowA + mi * 1024 + g1);
    }
#pragma unroll
    for (int ni = 0; ni < 2; ++ni) {
      b0[ni][0] = *(const bf16x8*)(Bt + rowB + ni * 1024 + g0);
      b0[ni][1] = *(const bf16x8*)(Bt + rowB + ni * 1024 + g1);
    }
    __builtin_amdgcn_s_barrier();
    asm volatile("s_waitcnt lgkmcnt(0)" ::: "memory");
    __builtin_amdgcn_s_setprio(1);
#pragma unroll
    for (int mi = 0; mi < 4; ++mi)
#pragma unroll
      for (int ni = 0; ni < 2; ++ni) {
        acc[mi][ni] = __builtin_amdgcn_mfma_f32_16x16x32_bf16(
            a[mi][0], b0[ni][0], acc[mi][ni], 0, 0, 0);
        acc[mi][ni] = __builtin_amdgcn_mfma_f32_16x16x32_bf16(
            a[mi][1], b0[ni][1], acc[mi][ni], 0, 0, 0);
      }
    __builtin_amdgcn_s_setprio(0);
    __builtin_amdgcn_s_barrier();

    // p1: read B ni2-3; stage A-miH0(t+2); MFMA (miH0,niH1)
#pragma unroll
    for (int ni = 0; ni < 2; ++ni) {
      b1[ni][0] = *(const bf16x8*)(Bt + rowB + (ni + 2) * 1024 + g0);
      b1[ni][1] = *(const bf16x8*)(Bt + rowB + (ni + 2) * 1024 + g1);
    }
    if (st) STG_A0(ko, q);
    __builtin_amdgcn_s_barrier();
    asm volatile("s_waitcnt lgkmcnt(0)" ::: "memory");
    __builtin_amdgcn_s_setprio(1);
#pragma unroll
    for (int mi = 0; mi < 4; ++mi)
#pragma unroll
      for (int ni = 0; ni < 2; ++ni) {
        acc[mi][ni + 2] = __builtin_amdgcn_mfma_f32_16x16x32_bf16(
            a[mi][0], b1[ni][0], acc[mi][ni + 2], 0, 0, 0);
        acc[mi][ni + 2] = __builtin_amdgcn_mfma_f32_16x16x32_bf16(
            a[mi][1], b1[ni][1], acc[mi][ni + 2], 0, 0, 0);
      }
    __builtin_amdgcn_s_setprio(0);
    __builtin_amdgcn_s_barrier();

    // p2: read A mi4-7; stage B-niH0(t+2); MFMA (miH1,niH1)
#pragma unroll
    for (int mi = 0; mi < 4; ++mi) {
      a[mi][0] = *(const bf16x8*)(At + rowA + (mi + 4) * 1024 + g0);
      a[mi][1] = *(const bf16x8*)(At + rowA + (mi + 4) * 1024 + g1);
    }
    if (st) STG_B0(ko, q);
    __builtin_amdgcn_s_barrier();
    asm volatile("s_waitcnt lgkmcnt(0)" ::: "memory");
    __builtin_amdgcn_s_setprio(1);
#pragma unroll
    for (int mi = 0; mi < 4; ++mi)
#pragma unroll
      for (int ni = 0; ni < 2; ++ni) {
        acc[mi + 4][ni + 2] = __builtin_amdgcn_mfma_f32_16x16x32_bf16(
            a[mi][0], b1[ni][0], acc[mi + 4][ni + 2], 0, 0, 0);
        acc[mi + 4][ni + 2] = __builtin_amdgcn_mfma_f32_16x16x32_bf16(
            a[mi][1], b1[ni][1], acc[mi + 4][ni + 2], 0, 0, 0);
      }
    __builtin_amdgcn_s_setprio(0);
    __builtin_amdgcn_s_barrier();

    // p3: stage B-niH1 + A-miH1; MFMA (miH1,niH0); counted vmcnt
    if (st) { STG_B1(ko, q); STG_A1(ko, q); }
    __builtin_amdgcn_s_barrier();
    __builtin_amdgcn_s_setprio(1);
#pragma unroll
    for (int mi = 0; mi < 4; ++mi)
#pragma unroll
      for (int ni = 0; ni < 2; ++ni) {
        acc[mi + 4][ni] = __builtin_amdgcn_mfma_f32_16x16x32_bf16(
            a[mi][0], b0[ni][0], acc[mi + 4][ni], 0, 0, 0);
        acc[mi + 4][ni] = __builtin_amdgcn_mfma_f32_16x16x32_bf16(
            a[mi][1], b0[ni][1], acc[mi + 4][ni], 0, 0, 0);
      }
    __builtin_amdgcn_s_setprio(0);
    if (st)
      asm volatile("s_waitcnt vmcnt(8)" ::: "memory");
    else
      asm volatile("s_waitcnt vmcnt(0)" ::: "memory");
    __builtin_amdgcn_s_barrier();
  }
#undef STG_B1
#undef STG_B0
#undef STG_A1
#undef STG_A0
#undef STG

  if constexpr (MODE == 0) {
    unsigned short* Cb = (unsigned short*)Cout;
#pragma unroll
    for (int mi = 0; mi < 8; ++mi) {
      const int grow = rowBase + waveM * 128 + mi * 16 + lq * 4;
#pragma unroll
      for (int ni = 0; ni < 4; ++ni) {
        const int gcol = colBase + waveN * 64 + ni * 16 + lrow;
#pragma unroll
        for (int r = 0; r < 4; ++r)
          Cb[(size_t)(grow + r) * ldc + gcol] = f2bf(acc[mi][ni][r]);
      }
    }
  }
}

// ---- wsum[k] = (1/S)·Σ_q e[q,k]/rowsum[q]; fp8 input, permuted cols -------
// R0 original: grid (S/64, B), q-chunk 64.
__global__ __launch_bounds__(256) void colsum_kernel(
    const unsigned int* __restrict__ Epk, const float* __restrict__ rowsum,
    float* __restrict__ wsum) {
  const int b = blockIdx.y, q0 = blockIdx.x * 64, t = threadIdx.x;
  __shared__ float rinv[64];
  if (t < 64) rinv[t] = 1.0f / rowsum[(size_t)b * S_ + q0 + t];
  __syncthreads();
  float cs[2][4] = {{0, 0, 0, 0}, {0, 0, 0, 0}};
  const unsigned int* Eb = Epk + ((size_t)b * S_ + q0) * (S_ / 4);
  for (int q = 0; q < 64; ++q) {
    const float rv = rinv[q];
    const unsigned int* row = Eb + (size_t)q * (S_ / 4);
#pragma unroll
    for (int j = 0; j < 2; ++j) {
      const unsigned int p = row[t + 256 * j];
      f32x2 lo = __builtin_amdgcn_cvt_pk_f32_fp8(p, false);
      f32x2 hi = __builtin_amdgcn_cvt_pk_f32_fp8(p, true);
      cs[j][0] += lo[0] * rv;
      cs[j][1] += lo[1] * rv;
      cs[j][2] += hi[0] * rv;
      cs[j][3] += hi[1] * rv;
    }
  }
  const float inv = 1.0f / (float)S_;
#pragma unroll
  for (int j = 0; j < 2; ++j) {
    const int d = t + 256 * j;
    const int base = (d >> 4) * 64 + (d & 15);
#pragma unroll
    for (int jj = 0; jj < 4; ++jj)
      atomicAdd(&wsum[(size_t)b * S_ + base + 16 * jj], cs[j][jj] * inv);
  }
}

// ---- xbar[b,e] = Σ_k wsum[b,k]·xbf[b,k,e]  (bf16 x) -----------------------
// R0 original: grid (16, B), k-chunk 128.
__global__ __launch_bounds__(256) void xbar_kernel(
    const unsigned short* __restrict__ xbf, const float* __restrict__ wsum,
    float* __restrict__ xbar) {
  const int b = blockIdx.y, kc = blockIdx.x, t = threadIdx.x;
  float4 acc = {0.f, 0.f, 0.f, 0.f};
  for (int k0 = 0; k0 < 128; ++k0) {
    const int k = kc * 128 + k0;
    const float w = wsum[(size_t)b * S_ + k];
    const ushort4 xv =
        *(const ushort4*)(xbf + ((size_t)b * S_ + k) * E_ + t * 4);
    acc.x += w * __uint_as_float((unsigned int)xv.x << 16);
    acc.y += w * __uint_as_float((unsigned int)xv.y << 16);
    acc.z += w * __uint_as_float((unsigned int)xv.z << 16);
    acc.w += w * __uint_as_float((unsigned int)xv.w << 16);
  }
  float* xb = xbar + (size_t)b * E_ + t * 4;
  atomicAdd(&xb[0], acc.x);
  atomicAdd(&xb[1], acc.y);
  atomicAdd(&xb[2], acc.z);
  atomicAdd(&xb[3], acc.w);
}

// ---- out[b,e] += Σ_{chunk} xbar[b,c]·wv[e,c] (+bv on chunk 0) -------------
__global__ __launch_bounds__(256) void out_kernel(
    const float* __restrict__ xbar, const float* __restrict__ wv,
    const float* __restrict__ bv, float* __restrict__ out) {
  const int gid = blockIdx.x * 256 + threadIdx.x;
  const int b = gid >> 10, e = gid & 1023;
  const int c0 = blockIdx.y * 64;
  const float4* xr = (const float4*)(xbar + (size_t)b * E_) + c0;
  const float4* wr = (const float4*)(wv + (size_t)e * E_) + c0;
  float s = 0.f;
  for (int j = 0; j < 64; ++j) {
    float4 a = xr[j], w = wr[j];
    s += a.x * w.x + a.y * w.y + a.z * w.z + a.w * w.w;
  }
  if (blockIdx.y == 0) s += bv[e];
  atomicAdd(&out[gid], s);
}

extern "C" void kernel_launch(void* const* d_in, const int* in_sizes, int n_in,
                              void* d_out, int out_size, void* d_ws,
                              size_t ws_size, hipStream_t stream) {
  const float* x = (const float*)d_in[0];
  const float* wq = (const float*)d_in[1];
  const float* bq = (const float*)d_in[2];
  const float* wk = (const float*)d_in[3];
  // bk cancels in softmax
  const float* wv = (const float*)d_in[5];
  const float* bv = (const float*)d_in[6];
  float* out = (float*)d_out;

  char* ws = (char*)d_ws;
  const size_t MB = 1ull << 20;
  // xbf(64MB) | y bf16(64MB) | Ebuf fp8(64MB) | WqT(2) | WkT(2) | Mt(2)
  // | Z: g(4KB) rowsum(128KB) wsum(128KB) xbar(64KB) | vs(128KB)
  unsigned short* xbf = (unsigned short*)(ws);
  unsigned short* y = (unsigned short*)(ws + 64 * MB);
  unsigned char* Ebuf = (unsigned char*)(ws + 128 * MB);
  unsigned short* WqT = (unsigned short*)(ws + 192 * MB);
  unsigned short* WkT = (unsigned short*)(ws + 194 * MB);
  unsigned short* Mt = (unsigned short*)(ws + 196 * MB);
  float* g = (float*)(ws + 198 * MB);
  float* rowsum = g + E_;
  float* wsum = rowsum + B_ * S_;
  float* xbar = wsum + B_ * S_;
  float* vs = xbar + B_ * E_;

  // 128 KiB dynamic LDS opt-in for the y 256² kernel
  hipFuncSetAttribute(reinterpret_cast<const void*>(gemm256<0>),
                      hipFuncAttributeMaxDynamicSharedMemorySize, 131072);

  hipMemsetAsync(g, 0, (size_t)(E_ + 2 * B_ * S_ + B_ * E_) * sizeof(float),
                 stream);
  hipMemsetAsync(out, 0, (size_t)B_ * E_ * sizeof(float), stream);

  gvec_kernel<<<dim3(E_ / 256, 32), 256, 0, stream>>>(wk, bq, g);
  cast_x_v_kernel<<<B_ * S_, 256, 0, stream>>>(x, g, xbf, vs);
  tcast_kernel<<<dim3(32, 32), 256, 0, stream>>>(wq, WqT);
  tcast_kernel<<<dim3(32, 32), 256, 0, stream>>>(wk, WkT);

  // Mt[e',e] = Σ_f wk[f,e']·wq[f,e]  (bf16 out) — 128², no swizzle
  gemm_bt<0><<<dim3(8, 8), 256, 0, stream>>>(
      WkT, WqT, (void*)Mt, nullptr, nullptr, 1.0f, E_, E_, E_, E_, 0, 0, 0);
  // y = x·M  (bf16 out) — 256² 8-phase (Mt L2-resident => pipeline fills)
  gemm256<0><<<dim3(E_ / 256, (B_ * S_) / 256), 512, 131072, stream>>>(
      xbf, Mt, (void*)y, nullptr, nullptr, 1.0f, E_, 0, 0, 0);
  // e[b,q,k] = exp(y_q·x_k/32 + vs[b,k]) -> fp8 π-permuted; rowsum fp32
  // 128² proven body, no swizzle (R7 = 141.9 µs, R11 = 142.3 µs)
  gemm_bt<1><<<dim3(S_ / 128, S_ / 128, B_), 256, 0, stream>>>(
      y, xbf, (void*)Ebuf, vs, rowsum, 0.03125f, E_, E_, E_, S_,
      (long long)S_ * E_, (long long)S_ * E_, (long long)S_ * S_);

  colsum_kernel<<<dim3(S_ / 64, B_), 256, 0, stream>>>(
      (const unsigned int*)Ebuf, rowsum, wsum);
  xbar_kernel<<<dim3(16, B_), 256, 0, stream>>>(xbf, wsum, xbar);
  out_kernel<<<dim3(B_ * E_ / 256, 4), 256, 0, stream>>>(xbar, wv, bv, out);
}